// Round 1
// baseline (202.747 us; speedup 1.0000x reference)
//
#include <hip/hip_runtime.h>
#include <math.h>

#define NUM_GRID 16
#define NCELLS   256          // 16*16 cells per map
#define THRESH   0.65f
#define NUM_FG   40
#define NUM_BG   1
#define MAX_PTS  42
#define T_DIM    8
#define C_DIM    4
#define H_DIM    1024
#define W_DIM    1024
#define NMAPS    (T_DIM * C_DIM)          // 32
#define MAP_ELEMS (H_DIM * W_DIM)         // 1048576
#define CELL_DIM 64                       // 1024/16

#define ROWS_PER_BLK 32                   // band height per block
#define BANDS_PER_MAP (H_DIM / ROWS_PER_BLK)  // 32
#define NHALF 2                           // 2 bands per 64-row cell stripe

// ---------------------------------------------------------------------------
// Kernel 1: one block per (map, 32-row band). 256 threads, thread t owns
// float4-column t of every row in the band -> each row iteration the block
// reads one full 4 KiB row contiguously (1 KiB per wave instruction).
// cx = t>>4 is FIXED per thread, so per-cell reduction is a 4-step shfl_xor
// within aligned 16-lane groups: no LDS, no barriers.
// Tracks only unmasked (max, min-idx-argmax) and (min, min-idx-argmin);
// the fg-masked stream is derived in kernel 2 (fgmax == amax when amax>THRESH,
// with identical tie-breaking argmin).
// ---------------------------------------------------------------------------
__global__ __launch_bounds__(256)
void cell_stats_kernel(const float* __restrict__ sim,
                       float* __restrict__ amax_o, int* __restrict__ amaxarg_o,
                       float* __restrict__ amin_o, int* __restrict__ aminarg_o) {
    const int b    = blockIdx.x;       // 0..NMAPS*BANDS_PER_MAP-1
    const int map  = b >> 5;           // band count per map = 32
    const int rb   = b & 31;
    const int t    = threadIdx.x;      // float4 column 0..255
    const int row0 = rb * ROWS_PER_BLK;

    const float* __restrict__ p =
        sim + (size_t)map * MAP_ELEMS + (size_t)row0 * W_DIM + (t << 2);
    int idx = (row0 << 10) + (t << 2);   // flat index within the map

    float mxv = -INFINITY; int mxi = 0;
    float mnv =  INFINITY; int mni = 0;

    // rows processed in increasing order; strict compares keep the SMALLEST
    // flat index among ties (per-thread indices increase monotonically).
    #pragma unroll 8
    for (int r = 0; r < ROWS_PER_BLK; ++r) {
        const float4 v = *reinterpret_cast<const float4*>(p);
        p += W_DIM;
        if (v.x > mxv) { mxv = v.x; mxi = idx;     }
        if (v.x < mnv) { mnv = v.x; mni = idx;     }
        if (v.y > mxv) { mxv = v.y; mxi = idx + 1; }
        if (v.y < mnv) { mnv = v.y; mni = idx + 1; }
        if (v.z > mxv) { mxv = v.z; mxi = idx + 2; }
        if (v.z < mnv) { mnv = v.z; mni = idx + 2; }
        if (v.w > mxv) { mxv = v.w; mxi = idx + 3; }
        if (v.w < mnv) { mnv = v.w; mni = idx + 3; }
        idx += W_DIM;
    }

    // Reduce across the 16 lanes sharing this thread's cx.
    // Groups [cx*16, cx*16+16) are aligned within the wave, so xor masks <16
    // never leave the group. Tie -> smaller flat index.
    #pragma unroll
    for (int d = 1; d < 16; d <<= 1) {
        const float v2 = __shfl_xor(mxv, d);
        const int   i2 = __shfl_xor(mxi, d);
        if (v2 > mxv || (v2 == mxv && i2 < mxi)) { mxv = v2; mxi = i2; }
        const float u2 = __shfl_xor(mnv, d);
        const int   j2 = __shfl_xor(mni, d);
        if (u2 < mnv || (u2 == mnv && j2 < mni)) { mnv = u2; mni = j2; }
    }

    if ((t & 15) == 0) {
        const int cx   = t >> 4;
        const int cy   = rb >> 1;          // 2 bands per 64-row cell stripe
        const int half = rb & 1;           // half 0 rows < half 1 rows
        const int o = half * (NMAPS * NCELLS) + (map << 8) + (cy << 4) + cx;
        amax_o[o] = mxv; amaxarg_o[o] = mxi;
        amin_o[o] = mnv; aminarg_o[o] = mni;
    }
}

// ---------------------------------------------------------------------------
// (value, index) block reduction over 256 threads (kernel 2 only).
// is_max: prefer larger value; else prefer smaller value. Ties -> smaller idx.
// ---------------------------------------------------------------------------
__device__ inline void block_reduce_pair(float& v, int& i, bool is_max,
                                         float* sv, int* si, int tid) {
    sv[tid] = v; si[tid] = i;
    __syncthreads();
    for (int s = 128; s > 0; s >>= 1) {
        if (tid < s) {
            float v2 = sv[tid + s]; int i2 = si[tid + s];
            float v1 = sv[tid];     int i1 = si[tid];
            bool take = is_max ? (v2 > v1 || (v2 == v1 && i2 < i1))
                               : (v2 < v1 || (v2 == v1 && i2 < i1));
            if (take) { sv[tid] = v2; si[tid] = i2; }
        }
        __syncthreads();
    }
    v = sv[0]; i = si[0];
    __syncthreads();   // safe reuse of sv/si afterwards
}

// ---------------------------------------------------------------------------
// Kernel 2: one block per map. 256 threads, one per cell.
// Merges the two band-halves per cell, derives the fg stream from THRESH,
// ranks cells (stable descending), emits top-40 fg rows + bg row + num.
// ---------------------------------------------------------------------------
__global__ __launch_bounds__(256)
void select_kernel(const float* __restrict__ amax_i, const int* __restrict__ amaxarg_i,
                   const float* __restrict__ amin_i, const int* __restrict__ aminarg_i,
                   const int* __restrict__ orig_sizes,
                   float* __restrict__ out_pts, float* __restrict__ out_nums) {
    const int m   = blockIdx.x;    // 0..31
    const int tid = threadIdx.x;   // cell id
    const int t   = m >> 2;        // map = t*C + c

    const float sx = (float)orig_sizes[t * 2 + 1] / (float)W_DIM;
    const float sy = (float)orig_sizes[t * 2 + 0] / (float)H_DIM;

    // merge the two halves of this cell (half0 indices < half1 indices,
    // so the tie-break naturally keeps the smaller flat index)
    const int o0 = m * NCELLS + tid;
    const int o1 = NMAPS * NCELLS + o0;
    float mxv = amax_i[o0]; int mxi = amaxarg_i[o0];
    { const float v2 = amax_i[o1]; const int i2 = amaxarg_i[o1];
      if (v2 > mxv || (v2 == mxv && i2 < mxi)) { mxv = v2; mxi = i2; } }
    float mnv = amin_i[o0]; int mni = aminarg_i[o0];
    { const float u2 = amin_i[o1]; const int j2 = aminarg_i[o1];
      if (u2 < mnv || (u2 == mnv && j2 < mni)) { mnv = u2; mni = j2; } }

    // derived fg stream: cell has fg pixels iff its max exceeds THRESH, and
    // the masked argmax (min flat idx among pixels == masked max) coincides
    // with the unmasked argmax in that case.
    const bool  valid = (mxv > THRESH);
    const float fgv   = valid ? mxv : -INFINITY;
    const int   fgi   = mxi;

    __shared__ float skey[256];
    skey[tid] = fgv;                        // key = valid ? score : -inf

    __shared__ float sv[256];
    __shared__ int   si[256];

    // global (unmasked) max with min-idx tie-break  -> jnp.argmax fallback
    float gv = mxv; int gi = mxi;
    block_reduce_pair(gv, gi, true, sv, si, tid);
    // global min with min-idx tie-break             -> top_k(-flat, 1)
    float bv = mnv; int bi = mni;
    block_reduce_pair(bv, bi, false, sv, si, tid);

    const int nvalid = __syncthreads_count(valid ? 1 : 0);
    const bool any_fg = (nvalid > 0);
    const int fg_count = any_fg ? (nvalid < NUM_FG ? nvalid : NUM_FG) : 1;

    // stable descending rank: #{j : key_j > key_i or (key_j == key_i and j < i)}
    int rank = 0;
    const float key = fgv;
    for (int j = 0; j < 256; ++j) {
        const float kj = skey[j];
        rank += (kj > key || (kj == key && j < tid)) ? 1 : 0;
    }

    __shared__ float outp[MAX_PTS * 4];
    if (tid < MAX_PTS * 4) outp[tid] = 0.0f;
    __syncthreads();

    if (any_fg && valid && rank < NUM_FG) {
        const int col = fgi & (W_DIM - 1);
        const int row = fgi >> 10;
        outp[rank * 4 + 0] = (float)col * sx;
        outp[rank * 4 + 1] = (float)row * sy;
        outp[rank * 4 + 2] = fgv;
        outp[rank * 4 + 3] = 1.0f;
    }
    if (!any_fg && tid == 0) {
        const int col = gi & (W_DIM - 1);
        const int row = gi >> 10;
        outp[0] = (float)col * sx;
        outp[1] = (float)row * sy;
        outp[2] = gv;
        outp[3] = 1.0f;
    }
    __syncthreads();

    if (tid == 0) {
        const int col = bi & (W_DIM - 1);
        const int row = bi >> 10;
        outp[fg_count * 4 + 0] = (float)col * sx;
        outp[fg_count * 4 + 1] = (float)row * sy;
        outp[fg_count * 4 + 2] = bv;
        outp[fg_count * 4 + 3] = 0.0f;
    }
    __syncthreads();

    if (tid < MAX_PTS * 4) out_pts[(size_t)m * (MAX_PTS * 4) + tid] = outp[tid];
    if (tid == 0) out_nums[m] = (float)(fg_count + NUM_BG);
}

// ---------------------------------------------------------------------------
extern "C" void kernel_launch(void* const* d_in, const int* in_sizes, int n_in,
                              void* d_out, int out_size, void* d_ws, size_t ws_size,
                              hipStream_t stream) {
    const float* sim        = (const float*)d_in[0];
    // d_in[1] = category_ids (unused by forward)
    const int*   orig_sizes = (const int*)d_in[2];

    float* out = (float*)d_out;
    float* out_pts  = out;                                   // (T,C,42,4) = 5376 floats
    float* out_nums = out + (size_t)NMAPS * MAX_PTS * 4;     // (T,C)      = 32 floats

    // workspace: 2 halves x 8192 cells, SoA (256 KiB total)
    const size_t NC = (size_t)NHALF * NMAPS * NCELLS;        // 16384
    char* ws = (char*)d_ws;
    float* amax_ws    = (float*)(ws + 0 * NC * 4);
    int*   amaxarg_ws = (int*)  (ws + 1 * NC * 4);
    float* amin_ws    = (float*)(ws + 2 * NC * 4);
    int*   aminarg_ws = (int*)  (ws + 3 * NC * 4);

    cell_stats_kernel<<<NMAPS * BANDS_PER_MAP, 256, 0, stream>>>(
        sim, amax_ws, amaxarg_ws, amin_ws, aminarg_ws);

    select_kernel<<<NMAPS, 256, 0, stream>>>(
        amax_ws, amaxarg_ws, amin_ws, aminarg_ws,
        orig_sizes, out_pts, out_nums);
}